// Round 12
// baseline (1152.240 us; speedup 1.0000x reference)
//
#include <hip/hip_runtime.h>
#include <hip/hip_bf16.h>

// ---------------------------------------------------------------------------
// DRSAR_FL_RNN: B=512, T=128, F=256, H=512, K=3
// R19 = gemm1 FUSED INTO scan4 as producer waves (R14 gemm1 deleted):
//   - 256 blocks x 768 thr: waves 0-7 = R11-form scan (unchanged math),
//     waves 8-11 = producers computing this block's xw (2 batch rows x 512
//     cols) chunk-by-chunk (16 timesteps) into LDS ck[2][16][1040] ushorts.
//   - Producer M-tile packs 8 timesteps x 2 rows = 16 (zero MFMA waste).
//     One (mt,ntloc) slice per scan step; chunk (t/16)+1 built during the
//     16 steps that consume chunk t/16; the existing per-step barrier is
//     the only synchronization (uniform across roles -> no deadlock path).
//   - Eliminates: gemm1's serial ~30-40us, xw2 64MB HBM write + 34MB read,
//     one launch gap. Producer work fits scan's measured idle issue slack
//     (MfmaUtil 42%, ~1190 cyc/step free).
//   - tloc stride 1040 ushorts (520 dwords = 16 mod 32): staging writes and
//     consumer reads are 2-way bank = free.
// prep_weights unchanged (also feeds wts to producers).
// ---------------------------------------------------------------------------

#define B_  512
#define T_  128
#define F_  256
#define H_  512
#define LOG2E 1.4426950408889634f

typedef __attribute__((ext_vector_type(8))) short short8;
typedef __attribute__((ext_vector_type(4))) float float4v;
typedef __attribute__((ext_vector_type(4))) int int4i;

__device__ inline ushort f2bf(float f) {
  __hip_bfloat16 h = __float2bfloat16(f);
  return *reinterpret_cast<ushort*>(&h);
}
__device__ inline float bf2f(unsigned u) { return __uint_as_float(u << 16); }
__device__ inline float fexp2(float x) { return __builtin_amdgcn_exp2f(x); }
__device__ inline float frcp(float x) { return __builtin_amdgcn_rcpf(x); }

// ws layout (bytes) — xw2 region retained but unused:
#define WS_W2I8 67108864
#define WS_WXF  67371008
#define WS_GP8  67633152
#define WS_BVEC 67649536
#define WS_WCV  67651584
#define WS_SCOL 67653632
#define WS_WTS  67657728

// blocks 0-31: Wh column-scales + i8 quant (frag-linear W2), coalesced reads.
// blocks 32-39: Wx -> WxF bf16 frag-linear via LDS transpose.
// block 40: tiny per-element prep: weights=sigmoid(theta), gating consts, b, Wc.
__global__ __launch_bounds__(256) void prep_weights(
    const float* __restrict__ Wh, const float* __restrict__ Wx,
    const float* __restrict__ theta, const float* __restrict__ b,
    const float* __restrict__ c, const float* __restrict__ sigma,
    const float* __restrict__ q, const float* __restrict__ Wc,
    int* __restrict__ W2, ushort* __restrict__ WxF,
    float* __restrict__ scol, float* __restrict__ out_w,
    float* __restrict__ gp8, float* __restrict__ bvec,
    float* __restrict__ wcv, float* __restrict__ wts) {
  __shared__ float lds[16544];  // 66176 B; reused by both roles
  const int t = threadIdx.x;

  if (blockIdx.x < 32) {
    const int nb = blockIdx.x;
    const int cc = t & 15, rg = t >> 4;
    float m = 0.f;
#pragma unroll
    for (int s = 0; s < 32; ++s)
      m = fmaxf(m, fabsf(Wh[(rg + s * 16) * H_ + nb * 16 + cc]));
    lds[rg * 16 + cc] = m;
    __syncthreads();
    if (t < 16) {
      float mm = lds[t];
#pragma unroll
      for (int s = 1; s < 16; ++s) mm = fmaxf(mm, lds[s * 16 + t]);
      mm = fmaxf(mm, 1e-20f);
      scol[nb * 16 + t] = mm / (127.f * 127.f);
      lds[256 + t] = 127.f / mm;
    }
    __syncthreads();
    const int lane = t & 63, dw = t >> 6;
    const int n = nb * 16 + (lane & 15);
    const float iv = lds[256 + (lane & 15)];
#pragma unroll
    for (int kt = 0; kt < 8; ++kt) {
      int pk = 0;
#pragma unroll
      for (int jj = 0; jj < 4; ++jj) {
        const int k = kt * 64 + ((lane >> 4) << 4) + dw * 4 + jj;
        int qv = (int)rintf(Wh[k * H_ + n] * iv);
        qv = min(127, max(-127, qv));
        pk |= (qv & 255) << (8 * jj);
      }
      W2[((kt * 32 + nb) * 64 + lane) * 4 + dw] = pk;
    }
  } else if (blockIdx.x < 40) {
    const int kt = blockIdx.x - 32;
#pragma unroll
    for (int it = 0; it < 16; ++it) {
      const int lin = (it * 256 + t) * 4;
      const float4 v = *(const float4*)(Wx + kt * 32 * H_ + lin);
      const int f = lin >> 9, n0 = lin & 511;
      lds[f * 517 + n0 + 0] = v.x;
      lds[f * 517 + n0 + 1] = v.y;
      lds[f * 517 + n0 + 2] = v.z;
      lds[f * 517 + n0 + 3] = v.w;
    }
    __syncthreads();
#pragma unroll
    for (int it = 0; it < 8; ++it) {
      const int o = (it * 256 + t) * 8;
      const int lane = (o >> 3) & 63, nb = o >> 9;
      const int n = nb * 16 + (lane & 15), fb = (lane >> 4) << 3;
      ushort v[8];
#pragma unroll
      for (int j = 0; j < 8; ++j) v[j] = f2bf(lds[(fb + j) * 517 + n]);
      *(short8*)(WxF + kt * 16384 + o) = *(short8*)v;
    }
  } else {
#pragma unroll
    for (int r = 0; r < 2; ++r) {
      const int i = t + r * 256;
      if (i < F_) {
        float w = 1.f / (1.f + __expf(-theta[i]));
        out_w[i] = w;
        wts[i] = w;
      }
      float a[3], cc[3], qq[3];
#pragma unroll
      for (int k = 0; k < 3; ++k) {
        float s = sigma[i * 3 + k];
        cc[k] = c[i * 3 + k];
        a[k] = -LOG2E / (2.f * s * s + 1e-8f);
        qq[k] = q[i * 3 + k];
      }
      gp8[i * 8 + 0] = cc[0];
      gp8[i * 8 + 1] = cc[1];
      gp8[i * 8 + 2] = cc[2];
      gp8[i * 8 + 3] = a[0];
      gp8[i * 8 + 4] = a[1];
      gp8[i * 8 + 5] = a[2];
      gp8[i * 8 + 6] = __uint_as_float((unsigned)f2bf(qq[0]) |
                                       ((unsigned)f2bf(qq[1]) << 16));
      gp8[i * 8 + 7] = __uint_as_float((unsigned)f2bf(qq[2]));
      bvec[i] = b[i];
      wcv[i] = Wc[i];
    }
  }
}

// Fused scan + xw producer. 256 blocks x 768 thr (12 waves):
//   waves 0-7: R11-form scan of 2 batch rows x 512 cols.
//   waves 8-11: producer — xw[t][col] = bf16(x*wts) @ WxF for this block's
//   2 rows, chunked 16 timesteps into ck[chunk&1], one slice per step.
__global__ __launch_bounds__(768) void scan_fused(
    const float* __restrict__ x, const ushort* __restrict__ WxF,
    const float* __restrict__ wts, const int4i* __restrict__ W2,
    const float* __restrict__ gp8, const float* __restrict__ bvec,
    const float* __restrict__ wcv, const float* __restrict__ scol,
    const float* __restrict__ bc, float* __restrict__ out) {
  __shared__ __align__(16) ushort ck[2][16][1040];  // 66560 B xw chunks
  __shared__ __align__(16) char hb[2][1152];        // h mirror, rows 0..1
  __shared__ float red[8][2];
  const int tid = threadIdx.x;
  const int lane = tid & 63, w = tid >> 6;
  const int col16 = lane & 15, quad = lane >> 4;
  const int bg = blockIdx.x;

  for (int i = tid; i < 576; i += 768) ((int*)hb)[i] = 0;

  // ---- scan-wave preamble (w<8); producers harmlessly compute in-bounds ----
  const int col = (w & 7) * 64 + lane;
  int4i bfr[8][4];
  if (w < 8) {
#pragma unroll
    for (int kt = 0; kt < 8; ++kt)
#pragma unroll
      for (int nt = 0; nt < 4; ++nt)
        bfr[kt][nt] = W2[(kt * 32 + w * 4 + nt) * 64 + lane];
  }
  const float bcol = bvec[col], scl = scol[col], wcl = wcv[col];
  float4v g0 = *(const float4v*)(gp8 + col * 8);
  float4v g1 = *(const float4v*)(gp8 + col * 8 + 4);
  const float c0v = g0[0], c1v = g0[1], c2v = g0[2];
  const float a0v = g0[3], a1v = g1[0], a2v = g1[1];
  unsigned p01 = __float_as_uint(g1[2]);
  const float q0v = bf2f(p01 & 0xffffu);
  const float q1v = bf2f(p01 >> 16);
  const float q2v = bf2f(__float_as_uint(g1[3]) & 0xffffu);
  const float b0v = -2.f * a0v * c0v, d0v = a0v * c0v * c0v;
  const float b1v = -2.f * a1v * c1v, d1v = a1v * c1v * c1v;
  const float b2v = -2.f * a2v * c2v, d2v = a2v * c2v * c2v;
  const unsigned wsel = (lane & 1) ? 0x0501u : 0x0004u;
  const int woff = col + ((lane & 1) ? 575 : 0);

  float hreg[2] = {0.f, 0.f};
  const int4i izero = {0, 0, 0, 0};
  int4i areg[8];
#pragma unroll
  for (int kt = 0; kt < 8; ++kt) areg[kt] = izero;  // lanes col16>=2 stay 0

  // ---- producer preamble (w>=8) ----
  const int pw = w - 8;                 // 0..3
  const int brow = col16 & 1;           // batch row within pair
  const int trow = col16 >> 1;          // timestep within 8-step half-chunk
  const float* xrow = x + (size_t)(2 * bg + brow) * T_ * F_;
  short8 afrag[8];
  const float4v zerof = {0.f, 0.f, 0.f, 0.f};

  // A-frag: lane holds A[m=col16][k=quad*8+j] = x[2bg+(m&1)][T0+mt*8+(m>>1)][k]*w[k]
  auto build_afrag = [&](int cpr, int mt) {
    const float* xr = xrow + (size_t)(cpr * 16 + mt * 8 + trow) * F_;
#pragma unroll
    for (int kt = 0; kt < 8; ++kt) {
      const int f0 = kt * 32 + quad * 8;
      float4 x0 = *(const float4*)(xr + f0);
      float4 x1 = *(const float4*)(xr + f0 + 4);
      float4 w0 = *(const float4*)(wts + f0);
      float4 w1 = *(const float4*)(wts + f0 + 4);
      ushort a[8];
      a[0] = f2bf(x0.x * w0.x); a[1] = f2bf(x0.y * w0.y);
      a[2] = f2bf(x0.z * w0.z); a[3] = f2bf(x0.w * w0.w);
      a[4] = f2bf(x1.x * w1.x); a[5] = f2bf(x1.y * w1.y);
      a[6] = f2bf(x1.z * w1.z); a[7] = f2bf(x1.w * w1.w);
      afrag[kt] = *(short8*)a;
    }
  };
  // slice: one Ntile nt2 for one mt; C m=quad*4+r -> tloc=mt*8+2q+(r>>1), row=r&1
  auto do_slice = [&](int cpr, int mt, int ntloc) {
    const int nt2 = pw * 8 + ntloc;
    float4v acc = zerof;
#pragma unroll
    for (int kt = 0; kt < 8; ++kt) {
      short8 bf = *(const short8*)(WxF + ((kt * 32 + nt2) * 64 + lane) * 8);
      acc = __builtin_amdgcn_mfma_f32_16x16x32_bf16(afrag[kt], bf, acc, 0, 0, 0);
    }
    ushort* bp = &ck[cpr & 1][mt * 8 + 2 * quad]
                   [(nt2 >> 2) * 128 + ((nt2 & 3) * 16 + col16) * 2];
    ushort2 lo, hi;
    lo.x = f2bf(acc[0]); lo.y = f2bf(acc[1]);
    hi.x = f2bf(acc[2]); hi.y = f2bf(acc[3]);
    *(ushort2*)bp = lo;
    *(ushort2*)(bp + 1040) = hi;  // tloc+1
  };

  // ---- prologue: producers build chunk 0 ----
  if (w >= 8) {
#pragma unroll
    for (int mt = 0; mt < 2; ++mt) {
      build_afrag(0, mt);
      for (int ntloc = 0; ntloc < 8; ++ntloc) do_slice(0, mt, ntloc);
    }
  }
  __syncthreads();  // chunk 0 visible; common rendezvous

#pragma clang loop unroll(disable)
  for (int t = 0; t < T_; ++t) {
    if (w < 8) {
      // consume chunk t>>4 (parity (t>>4)&1), built >=1 barrier ago
      unsigned xv = *(const unsigned*)&ck[(t >> 4) & 1][t & 15][w * 128 + lane * 2];

      if (col16 < 2) {
        const char* abase = hb[t & 1] + col16 * 576;
#pragma unroll
        for (int kt = 0; kt < 8; ++kt)
          areg[kt] = *(const int4i*)(abase + kt * 64 + (quad << 4));
      }

      // pair A: nt 0,1 chains
      int4i acc0 = izero, acc1 = izero;
#pragma unroll
      for (int kt = 0; kt < 8; ++kt) {
        acc0 = __builtin_amdgcn_mfma_i32_16x16x64_i8(areg[kt], bfr[kt][0], acc0, 0, 0, 0);
        acc1 = __builtin_amdgcn_mfma_i32_16x16x64_i8(areg[kt], bfr[kt][1], acc1, 0, 0, 0);
      }
      int t0[2], t1[2];
#pragma unroll
      for (int rg = 0; rg < 2; ++rg) {
        t0[rg] = __shfl(acc0[rg], col16, 64);
        t1[rg] = __shfl(acc1[rg], col16, 64);
      }
      // pair B: nt 2,3 chains
      int4i acc2 = izero, acc3 = izero;
#pragma unroll
      for (int kt = 0; kt < 8; ++kt) {
        acc2 = __builtin_amdgcn_mfma_i32_16x16x64_i8(areg[kt], bfr[kt][2], acc2, 0, 0, 0);
        acc3 = __builtin_amdgcn_mfma_i32_16x16x64_i8(areg[kt], bfr[kt][3], acc3, 0, 0, 0);
      }
      int t2[2], t3[2];
#pragma unroll
      for (int rg = 0; rg < 2; ++rg) {
        t2[rg] = __shfl(acc2[rg], col16, 64);
        t3[rg] = __shfl(acc3[rg], col16, 64);
      }

      int accq[2];
#pragma unroll
      for (int rg = 0; rg < 2; ++rg) {
        int sA = (quad & 1) ? t1[rg] : t0[rg];
        int sB = (quad & 1) ? t3[rg] : t2[rg];
        accq[rg] = (quad & 2) ? sB : sA;
      }

      int qb[2];
#pragma unroll
      for (int rg = 0; rg < 2; ++rg) {
        float v = __uint_as_float(rg ? (xv & 0xffff0000u) : (xv << 16));
        float z = v + bcol + (float)accq[rg] * scl;
        float e = fexp2(v * (2.f * LOG2E));
        float nw = 1.f - 2.f * frcp(1.f + e);            // tanh(v)
        float zz = z * z;
        float m0 = fexp2(fmaf(a0v, zz, fmaf(b0v, z, d0v)));
        float m1 = fexp2(fmaf(a1v, zz, fmaf(b1v, z, d1v)));
        float m2 = fexp2(fmaf(a2v, zz, fmaf(b2v, z, d2v)));
        float num = m0 * q0v + m1 * q1v + m2 * q2v;
        float den = m0 + m1 + m2 + 1e-8f;
        float s = num * frcp(den);
        float gg = frcp(1.f + fexp2(-s * LOG2E));        // sigmoid(s)
        float h = hreg[rg] + gg * (nw - hreg[rg]);
        hreg[rg] = h;
        qb[rg] = (int)rintf(h * 127.f);
      }

      if (t < T_ - 1) {
        int pk = (int)__builtin_amdgcn_perm((unsigned)qb[1], (unsigned)qb[0], 0x0400u);
        unsigned p1 = (unsigned)__shfl_xor(pk, 1, 64);
        unsigned v16 = __builtin_amdgcn_perm((unsigned)pk, p1, wsel);
        *(ushort*)(hb[(t + 1) & 1] + woff) = (ushort)v16;
      }
    } else {
      // producer: build chunk (t>>4)+1, slice t&15
      const int cpr = (t >> 4) + 1;
      if (cpr < 8) {
        const int sl = t & 15, mt = sl >> 3, ntloc = sl & 7;
        if (ntloc == 0) build_afrag(cpr, mt);
        do_slice(cpr, mt, ntloc);
      }
    }
    if (t < T_ - 1) __syncthreads();
  }

  if (w < 8) {
    float part[2];
#pragma unroll
    for (int rg = 0; rg < 2; ++rg) {
      part[rg] = hreg[rg] * wcl;
#pragma unroll
      for (int m = 1; m < 64; m <<= 1) part[rg] += __shfl_xor(part[rg], m, 64);
    }
    if (lane == 0) {
      red[w][0] = part[0];
      red[w][1] = part[1];
    }
  }
  __syncthreads();
  if (tid < 2) {
    float s = bc[0];
#pragma unroll
    for (int ww = 0; ww < 8; ++ww) s += red[ww][tid];
    out[bg * 2 + tid] = s;
  }
}

extern "C" void kernel_launch(void* const* d_in, const int* in_sizes, int n_in,
                              void* d_out, int out_size, void* d_ws, size_t ws_size,
                              hipStream_t stream) {
  const float* x     = (const float*)d_in[0];
  const float* theta = (const float*)d_in[1];
  const float* Wx    = (const float*)d_in[2];
  const float* Wh    = (const float*)d_in[3];
  const float* b     = (const float*)d_in[4];
  const float* c     = (const float*)d_in[5];
  const float* sigma = (const float*)d_in[6];
  const float* q     = (const float*)d_in[7];
  const float* Wc    = (const float*)d_in[8];
  const float* bc    = (const float*)d_in[9];
  float* out = (float*)d_out;

  int*    W2  = (int*)((char*)d_ws + WS_W2I8);
  ushort* WxF = (ushort*)((char*)d_ws + WS_WXF);
  float*  gp8 = (float*)((char*)d_ws + WS_GP8);
  float*  bv  = (float*)((char*)d_ws + WS_BVEC);
  float*  wcv = (float*)((char*)d_ws + WS_WCV);
  float*  scl = (float*)((char*)d_ws + WS_SCOL);
  float*  wts = (float*)((char*)d_ws + WS_WTS);

  hipLaunchKernelGGL(prep_weights, dim3(41), dim3(256), 0, stream,
                     Wh, Wx, theta, b, c, sigma, q, Wc,
                     W2, WxF, scl, out + B_, gp8, bv, wcv, wts);
  hipLaunchKernelGGL(scan_fused, dim3(256), dim3(768), 0, stream,
                     x, WxF, wts, (const int4i*)W2, gp8, bv, wcv, scl, bc, out);
}

// Round 13
// 249.914 us; speedup vs baseline: 4.6105x; 4.6105x over previous
//
#include <hip/hip_runtime.h>
#include <hip/hip_bf16.h>

// ---------------------------------------------------------------------------
// DRSAR_FL_RNN: B=512, T=128, F=256, H=512, K=3
// R20 = R14 (best passing: 250.5us) with prep_weights' quant pass rebuilt:
//   OLD: 32 scalar loads/thread at 2KB stride (64B line per 4B used, 16x
//        overfetch, latency-exposed on 32 blocks).
//   NEW: per kt, stage the 64x16 Wh tile coalesced (float4 rows) into
//        LDS [64][17], then gather k-major per lane (2-way banks = free).
//        Bit-identical W2 (same values, pack order, index).
// This is the discriminating experiment for the ~78us prep+overhead residue
// seen in R14/R17/R19: big drop => prep was fat; neutral => fixed harness
// overhead, and we are at the structural floor.
// gemm1 + scan4 = R14/R11 forms (R19's fusion reverted: L2 thrash, 2.8GB).
// ---------------------------------------------------------------------------

#define B_  512
#define T_  128
#define F_  256
#define H_  512
#define LOG2E 1.4426950408889634f

// xw2 per-timestep stride in ushorts: [256 bg][8 w][64 lane][2 el]
#define XW_T_STRIDE 262144

typedef __attribute__((ext_vector_type(8))) short short8;
typedef __attribute__((ext_vector_type(4))) float float4v;
typedef __attribute__((ext_vector_type(4))) int int4i;

__device__ inline ushort f2bf(float f) {
  __hip_bfloat16 h = __float2bfloat16(f);
  return *reinterpret_cast<ushort*>(&h);
}
__device__ inline float bf2f(unsigned u) { return __uint_as_float(u << 16); }
__device__ inline float fexp2(float x) { return __builtin_amdgcn_exp2f(x); }
__device__ inline float frcp(float x) { return __builtin_amdgcn_rcpf(x); }

// ws layout (bytes):
//   xw2  bf16 [T][256 bg][8 w][64 lane][2 el]          : 0 .. 67108864
//   W2I8 i8 frag-linear [8 kt][32 nb][64 lane][16 B]   : 67108864 (262144)
//   WXF  bf16 frag-linear [8 kt][32 nb][64 lane][8]    : 67371008 (262144)
//   GP8  f32 [512][8]                                  : 67633152 (16384)
//   BVEC f32 [512]                                     : 67649536
//   WCV  f32 [512]                                     : 67651584
//   SCOL f32 [512]                                     : 67653632
//   WTS  f32 [256]                                     : 67657728
#define WS_W2I8 67108864
#define WS_WXF  67371008
#define WS_GP8  67633152
#define WS_BVEC 67649536
#define WS_WCV  67651584
#define WS_SCOL 67653632
#define WS_WTS  67657728

// blocks 0-31: Wh column-scales + i8 quant via coalesced LDS-transpose.
// blocks 32-39: Wx -> WxF bf16 frag-linear via LDS transpose.
// block 40: tiny per-element prep: weights=sigmoid(theta), gating consts, b, Wc.
__global__ __launch_bounds__(256) void prep_weights(
    const float* __restrict__ Wh, const float* __restrict__ Wx,
    const float* __restrict__ theta, const float* __restrict__ b,
    const float* __restrict__ c, const float* __restrict__ sigma,
    const float* __restrict__ q, const float* __restrict__ Wc,
    int* __restrict__ W2, ushort* __restrict__ WxF,
    float* __restrict__ scol, float* __restrict__ out_w,
    float* __restrict__ gp8, float* __restrict__ bvec,
    float* __restrict__ wcv, float* __restrict__ wts) {
  __shared__ float lds[16544];  // 66176 B; reused by all roles
  const int t = threadIdx.x;

  if (blockIdx.x < 32) {
    const int nb = blockIdx.x;
    // phase 1: column absmax over 16 cols, coalesced 64B runs
    const int cc = t & 15, rg = t >> 4;
    float m = 0.f;
#pragma unroll
    for (int s = 0; s < 32; ++s)
      m = fmaxf(m, fabsf(Wh[(rg + s * 16) * H_ + nb * 16 + cc]));
    lds[rg * 16 + cc] = m;
    __syncthreads();
    if (t < 16) {
      float mm = lds[t];
#pragma unroll
      for (int s = 1; s < 16; ++s) mm = fmaxf(mm, lds[s * 16 + t]);
      mm = fmaxf(mm, 1e-20f);
      scol[nb * 16 + t] = mm / (127.f * 127.f);
      lds[256 + t] = 127.f / mm;
    }
    __syncthreads();
    // phase 2: quantize via coalesced LDS-transpose (bit-identical to the
    // old strided-scalar path). tile at lds+512: [64][17] f32.
    const int lane = t & 63, dw = t >> 6;
    const float iv = lds[256 + (lane & 15)];
    const int r = t >> 2, cg = t & 3;   // stage role: tile row r, col-group cg
    const int kb = ((lane >> 4) << 4) + dw * 4;  // gather: local k base
    float* tile = lds + 512;
#pragma clang loop unroll(disable)
    for (int kt = 0; kt < 8; ++kt) {
      float4 v = *(const float4*)(Wh + (size_t)(kt * 64 + r) * H_ + nb * 16 + cg * 4);
      tile[r * 17 + cg * 4 + 0] = v.x;
      tile[r * 17 + cg * 4 + 1] = v.y;
      tile[r * 17 + cg * 4 + 2] = v.z;
      tile[r * 17 + cg * 4 + 3] = v.w;
      __syncthreads();
      int pk = 0;
#pragma unroll
      for (int jj = 0; jj < 4; ++jj) {
        int qv = (int)rintf(tile[(kb + jj) * 17 + (lane & 15)] * iv);
        qv = min(127, max(-127, qv));
        pk |= (qv & 255) << (8 * jj);
      }
      W2[((kt * 32 + nb) * 64 + lane) * 4 + dw] = pk;
      __syncthreads();  // protect tile before next kt overwrites
    }
  } else if (blockIdx.x < 40) {
    const int kt = blockIdx.x - 32;
    // stage Wx rows [kt*32, kt*32+32) x 512 into LDS, row stride 517
#pragma unroll
    for (int it = 0; it < 16; ++it) {
      const int lin = (it * 256 + t) * 4;
      const float4 v = *(const float4*)(Wx + kt * 32 * H_ + lin);
      const int f = lin >> 9, n0 = lin & 511;
      lds[f * 517 + n0 + 0] = v.x;
      lds[f * 517 + n0 + 1] = v.y;
      lds[f * 517 + n0 + 2] = v.z;
      lds[f * 517 + n0 + 3] = v.w;
    }
    __syncthreads();
    // write frag-linear: o = (nb*64+lane)*8 + j, coalesced 16B/lane runs
#pragma unroll
    for (int it = 0; it < 8; ++it) {
      const int o = (it * 256 + t) * 8;
      const int lane = (o >> 3) & 63, nb = o >> 9;
      const int n = nb * 16 + (lane & 15), fb = (lane >> 4) << 3;
      ushort v[8];
#pragma unroll
      for (int j = 0; j < 8; ++j) v[j] = f2bf(lds[(fb + j) * 517 + n]);
      *(short8*)(WxF + kt * 16384 + o) = *(short8*)v;
    }
  } else {
    // ex prep_small: 256 threads handle 512 items (i = t, t+256)
#pragma unroll
    for (int r = 0; r < 2; ++r) {
      const int i = t + r * 256;
      if (i < F_) {
        float w = 1.f / (1.f + __expf(-theta[i]));
        out_w[i] = w;
        wts[i] = w;
      }
      float a[3], cc[3], qq[3];
#pragma unroll
      for (int k = 0; k < 3; ++k) {
        float s = sigma[i * 3 + k];
        cc[k] = c[i * 3 + k];
        a[k] = -LOG2E / (2.f * s * s + 1e-8f);
        qq[k] = q[i * 3 + k];
      }
      gp8[i * 8 + 0] = cc[0];
      gp8[i * 8 + 1] = cc[1];
      gp8[i * 8 + 2] = cc[2];
      gp8[i * 8 + 3] = a[0];
      gp8[i * 8 + 4] = a[1];
      gp8[i * 8 + 5] = a[2];
      gp8[i * 8 + 6] = __uint_as_float((unsigned)f2bf(qq[0]) |
                                       ((unsigned)f2bf(qq[1]) << 16));
      gp8[i * 8 + 7] = __uint_as_float((unsigned)f2bf(qq[2]));
      bvec[i] = b[i];
      wcv[i] = Wc[i];
    }
  }
}

// xw2 = bf16(x*wts) @ bf16(Wx), 2 timesteps per block for B-frag reuse.
// grid (tt2=64, bblk64=8), 256 thr. (R14 form, best measured.)
__global__ __launch_bounds__(256, 2) void gemm1_kernel(
    const float* __restrict__ x, const float* __restrict__ wts,
    const ushort* __restrict__ WxF, ushort* __restrict__ xw2) {
  __shared__ ushort A2[2][64][256];  // 64KB, XOR-swizzled 16B chunks by row
  const int tid = threadIdx.x;
  const int lane = tid & 63, wg = tid >> 6;
  const int col16 = lane & 15, quad = lane >> 4;
  const int tt2 = blockIdx.x, bb = blockIdx.y;

  {  // stage A for both timesteps; wave reads contiguous 1KB rows
    const float4 wv = *(const float4*)(wts + lane * 4);
#pragma unroll
    for (int s = 0; s < 2; ++s) {
      const int t = tt2 + s * 64;
#pragma unroll
      for (int it = 0; it < 16; ++it) {
        const int row = it * 4 + wg;
        float4 xv = *(const float4*)(x + ((size_t)(bb * 64 + row) * T_ + t) * F_ + lane * 4);
        ushort4 o;
        o.x = f2bf(xv.x * wv.x);
        o.y = f2bf(xv.y * wv.y);
        o.z = f2bf(xv.z * wv.z);
        o.w = f2bf(xv.w * wv.w);
        const int ki = (lane * 4) ^ ((row & 7) << 3);  // 16B-chunk XOR swizzle
        *(ushort4*)&A2[s][row][ki] = o;
      }
    }
  }
  __syncthreads();

  const float4v zero = {0.f, 0.f, 0.f, 0.f};
  const int arow = wg * 16 + col16;
#pragma unroll
  for (int nn = 0; nn < 2; ++nn) {
    float4v acc0[16], acc1[16];
#pragma unroll
    for (int i = 0; i < 16; ++i) { acc0[i] = zero; acc1[i] = zero; }
#pragma unroll
    for (int kt = 0; kt < 8; ++kt) {
      short8 bfv[16];
#pragma unroll
      for (int nt = 0; nt < 16; ++nt)
        bfv[nt] = *(const short8*)(WxF + ((kt * 32 + nn * 16 + nt) * 64 + lane) * 8);
      const int ki = (kt * 32 + quad * 8) ^ ((arow & 7) << 3);
      short8 af0 = *(const short8*)&A2[0][arow][ki];
      short8 af1 = *(const short8*)&A2[1][arow][ki];
#pragma unroll
      for (int nt = 0; nt < 16; ++nt) {
        acc0[nt] = __builtin_amdgcn_mfma_f32_16x16x32_bf16(af0, bfv[nt], acc0[nt], 0, 0, 0);
        acc1[nt] = __builtin_amdgcn_mfma_f32_16x16x32_bf16(af1, bfv[nt], acc1[nt], 0, 0, 0);
      }
    }
    // store into scan4 layout for both timesteps (unchanged)
#pragma unroll
    for (int s = 0; s < 2; ++s) {
      const int t = tt2 + s * 64;
#pragma unroll
      for (int nt = 0; nt < 16; ++nt) {
        const float4v a = s ? acc1[nt] : acc0[nt];
        ushort2 lo, hi;
        lo.x = f2bf(a[0]);
        lo.y = f2bf(a[1]);
        hi.x = f2bf(a[2]);
        hi.y = f2bf(a[3]);
        const int bg0 = bb * 32 + wg * 8 + quad * 2;
        const size_t off0 =
            (((size_t)t * 256 + bg0) * 8 + nn * 4 + (nt >> 2)) * 128 +
            ((nt & 3) * 16 + col16) * 2;
        *(ushort2*)(xw2 + off0) = lo;
        *(ushort2*)(xw2 + off0 + 1024) = hi;  // bg0+1
      }
    }
  }
}

// scan4 (= R11, best measured): 256 WGs x 512 thr; WG owns 2 batch rows;
// wave owns 64 cols. 2-row h mirror (stride 576, conflict-free); nt-pair
// MFMA chains with pair-A bpermute spread hidden under pair-B; fma-form
// Gaussian; v_perm qb pack.
__global__ __launch_bounds__(512, 2) void scan4_kernel(
    const ushort* __restrict__ xw2, const int4i* __restrict__ W2,
    const float* __restrict__ gp8, const float* __restrict__ bvec,
    const float* __restrict__ wcv, const float* __restrict__ scol,
    const float* __restrict__ bc, float* __restrict__ out) {
  __shared__ __align__(16) char hb[2][1152];  // [buf][row*576 + k], rows 0..1
  __shared__ float red[8][2];
  const int tid = threadIdx.x;
  const int lane = tid & 63, w = tid >> 6;
  const int col16 = lane & 15, quad = lane >> 4;
  const int bg = blockIdx.x;

  for (int i = tid; i < 576; i += 512) ((int*)hb)[i] = 0;

  int4i bfr[8][4];
#pragma unroll
  for (int kt = 0; kt < 8; ++kt)
#pragma unroll
    for (int nt = 0; nt < 4; ++nt)
      bfr[kt][nt] = W2[(kt * 32 + w * 4 + nt) * 64 + lane];

  const int col = w * 64 + lane;
  const float bcol = bvec[col], scl = scol[col], wcl = wcv[col];
  float4v g0 = *(const float4v*)(gp8 + col * 8);
  float4v g1 = *(const float4v*)(gp8 + col * 8 + 4);
  const float c0v = g0[0], c1v = g0[1], c2v = g0[2];
  const float a0v = g0[3], a1v = g1[0], a2v = g1[1];
  unsigned p01 = __float_as_uint(g1[2]);
  const float q0v = bf2f(p01 & 0xffffu);
  const float q1v = bf2f(p01 >> 16);
  const float q2v = bf2f(__float_as_uint(g1[3]) & 0xffffu);
  // fma-form Gaussian: m = exp2(a*z^2 + b*z + d), b=-2ac, d=a*c^2
  const float b0v = -2.f * a0v * c0v, d0v = a0v * c0v * c0v;
  const float b1v = -2.f * a1v * c1v, d1v = a1v * c1v * c1v;
  const float b2v = -2.f * a2v * c2v, d2v = a2v * c2v * c2v;

  // write-back pack: even lane stores row0 (cols c,c+1), odd lane row1
  // (cols c-1,c). v_perm sel: 0-3 pick bytes of src1(p1), 4-7 of src0(pk).
  const unsigned wsel = (lane & 1) ? 0x0501u : 0x0004u;
  const int woff = col + ((lane & 1) ? 575 : 0);

  float hreg[2] = {0.f, 0.f};
  const int4i izero = {0, 0, 0, 0};
  int4i areg[8];
#pragma unroll
  for (int kt = 0; kt < 8; ++kt) areg[kt] = izero;  // lanes col16>=2 stay 0

  const ushort* xwb = xw2 + ((size_t)bg * 8 + w) * 128 + lane * 2;
  unsigned xv = *(const unsigned*)xwb;
  unsigned xn;
  __syncthreads();

#pragma clang loop unroll(disable)
  for (int t = 0; t < T_; ++t) {
    const int tn = (t + 1) & 127;
    xn = *(const unsigned*)(xwb + (size_t)tn * XW_T_STRIDE);

    if (col16 < 2) {
      const char* abase = hb[t & 1] + col16 * 576;
#pragma unroll
      for (int kt = 0; kt < 8; ++kt)
        areg[kt] = *(const int4i*)(abase + kt * 64 + (quad << 4));
    }

    // pair A: nt 0,1 chains
    int4i acc0 = izero, acc1 = izero;
#pragma unroll
    for (int kt = 0; kt < 8; ++kt) {
      acc0 = __builtin_amdgcn_mfma_i32_16x16x64_i8(areg[kt], bfr[kt][0], acc0, 0, 0, 0);
      acc1 = __builtin_amdgcn_mfma_i32_16x16x64_i8(areg[kt], bfr[kt][1], acc1, 0, 0, 0);
    }
    // early spread of pair A (DS pipe is free while pair B MFMAs run)
    int t0[2], t1[2];
#pragma unroll
    for (int rg = 0; rg < 2; ++rg) {
      t0[rg] = __shfl(acc0[rg], col16, 64);
      t1[rg] = __shfl(acc1[rg], col16, 64);
    }
    // pair B: nt 2,3 chains
    int4i acc2 = izero, acc3 = izero;
#pragma unroll
    for (int kt = 0; kt < 8; ++kt) {
      acc2 = __builtin_amdgcn_mfma_i32_16x16x64_i8(areg[kt], bfr[kt][2], acc2, 0, 0, 0);
      acc3 = __builtin_amdgcn_mfma_i32_16x16x64_i8(areg[kt], bfr[kt][3], acc3, 0, 0, 0);
    }
    int t2[2], t3[2];
#pragma unroll
    for (int rg = 0; rg < 2; ++rg) {
      t2[rg] = __shfl(acc2[rg], col16, 64);
      t3[rg] = __shfl(acc3[rg], col16, 64);
    }

    int accq[2];
#pragma unroll
    for (int rg = 0; rg < 2; ++rg) {
      int sA = (quad & 1) ? t1[rg] : t0[rg];
      int sB = (quad & 1) ? t3[rg] : t2[rg];
      accq[rg] = (quad & 2) ? sB : sA;
    }

    int qb[2];
#pragma unroll
    for (int rg = 0; rg < 2; ++rg) {
      float v = __uint_as_float(rg ? (xv & 0xffff0000u) : (xv << 16));
      float z = v + bcol + (float)accq[rg] * scl;
      float e = fexp2(v * (2.f * LOG2E));
      float nw = 1.f - 2.f * frcp(1.f + e);            // tanh(v)
      float zz = z * z;
      float m0 = fexp2(fmaf(a0v, zz, fmaf(b0v, z, d0v)));
      float m1 = fexp2(fmaf(a1v, zz, fmaf(b1v, z, d1v)));
      float m2 = fexp2(fmaf(a2v, zz, fmaf(b2v, z, d2v)));
      float num = m0 * q0v + m1 * q1v + m2 * q2v;
      float den = m0 + m1 + m2 + 1e-8f;
      float s = num * frcp(den);
      float gg = frcp(1.f + fexp2(-s * LOG2E));        // sigmoid(s)
      float h = hreg[rg] + gg * (nw - hreg[rg]);
      hreg[rg] = h;
      qb[rg] = (int)rintf(h * 127.f);
    }

    if (t < T_ - 1) {
      // pk byte0 = qb0.b0, byte1 = qb1.b0
      int pk = (int)__builtin_amdgcn_perm((unsigned)qb[1], (unsigned)qb[0], 0x0400u);
      unsigned p1 = (unsigned)__shfl_xor(pk, 1, 64);
      unsigned v16 = __builtin_amdgcn_perm((unsigned)pk, p1, wsel);
      *(ushort*)(hb[(t + 1) & 1] + woff) = (ushort)v16;
      __syncthreads();
    }
    xv = xn;
  }

  float part[2];
#pragma unroll
  for (int rg = 0; rg < 2; ++rg) {
    part[rg] = hreg[rg] * wcl;
#pragma unroll
    for (int m = 1; m < 64; m <<= 1) part[rg] += __shfl_xor(part[rg], m, 64);
  }
  if (lane == 0) {
    red[w][0] = part[0];
    red[w][1] = part[1];
  }
  __syncthreads();
  if (tid < 2) {
    float s = bc[0];
#pragma unroll
    for (int ww = 0; ww < 8; ++ww) s += red[ww][tid];
    out[bg * 2 + tid] = s;
  }
}

extern "C" void kernel_launch(void* const* d_in, const int* in_sizes, int n_in,
                              void* d_out, int out_size, void* d_ws, size_t ws_size,
                              hipStream_t stream) {
  const float* x     = (const float*)d_in[0];
  const float* theta = (const float*)d_in[1];
  const float* Wx    = (const float*)d_in[2];
  const float* Wh    = (const float*)d_in[3];
  const float* b     = (const float*)d_in[4];
  const float* c     = (const float*)d_in[5];
  const float* sigma = (const float*)d_in[6];
  const float* q     = (const float*)d_in[7];
  const float* Wc    = (const float*)d_in[8];
  const float* bc    = (const float*)d_in[9];
  float* out = (float*)d_out;

  ushort* xw2 = (ushort*)d_ws;
  int*    W2  = (int*)((char*)d_ws + WS_W2I8);
  ushort* WxF = (ushort*)((char*)d_ws + WS_WXF);
  float*  gp8 = (float*)((char*)d_ws + WS_GP8);
  float*  bv  = (float*)((char*)d_ws + WS_BVEC);
  float*  wcv = (float*)((char*)d_ws + WS_WCV);
  float*  scl = (float*)((char*)d_ws + WS_SCOL);
  float*  wts = (float*)((char*)d_ws + WS_WTS);

  hipLaunchKernelGGL(prep_weights, dim3(41), dim3(256), 0, stream,
                     Wh, Wx, theta, b, c, sigma, q, Wc,
                     W2, WxF, scl, out + B_, gp8, bv, wcv, wts);
  hipLaunchKernelGGL(gemm1_kernel, dim3(64, 8), dim3(256), 0, stream,
                     x, wts, WxF, xw2);
  hipLaunchKernelGGL(scan4_kernel, dim3(256), dim3(512), 0, stream,
                     xw2, (const int4i*)W2, gp8, bv, wcv, scl, bc, out);
}